// Round 11
// baseline (125.897 us; speedup 1.0000x reference)
//
#include <hip/hip_runtime.h>
#include <hip/hip_bf16.h>
#include <cstddef>

#define B_ 8
#define H_ 12
#define N_ 2048
#define D_ 64
#define M_ 256
#define BH_ (B_*H_)

typedef __attribute__((ext_vector_type(8))) short short8v;
typedef __attribute__((ext_vector_type(4))) float f32x4;

static __device__ __forceinline__ float4 ld4(const float* p){ return *(const float4*)p; }

static __device__ __forceinline__ unsigned short f2bf(float x){
    union { float f; unsigned int u; } v; v.f = x;
    unsigned int r = v.u + 0x7FFFu + ((v.u >> 16) & 1u);
    return (unsigned short)(r >> 16);
}
static __device__ __forceinline__ unsigned int pack2(float a, float b){
    return (unsigned int)f2bf(a) | ((unsigned int)f2bf(b) << 16);
}

// ---------------- K0: Dct fp32 -> DctA (MFMA frag-linear bf16) + DctT bf16 ----
// DctA layout: frag (fm, fk) covers rows [16fm,16fm+16) x k [32fk, 32fk+32).
// Element (lane, j): row = 16fm + (lane&15), k = 32fk + (lane>>4)*8 + j.
// Linear: DctA[((fm*64 + fk)*64 + lane)*8 + j]  -> a wave A-frag load is one
// coalesced 1 KB global_load_dwordx4. 1 MB total, L2-resident, shared by all.
__global__ __launch_bounds__(256)
void dct_prep_kernel(const float* __restrict__ Dct, unsigned short* __restrict__ DctA,
                     unsigned short* __restrict__ DctT)
{
    __shared__ __align__(16) unsigned short T[64*72];
    const int n0 = blockIdx.x * 64, m0 = blockIdx.y * 64;
    const int tid = threadIdx.x;
    const int mrow = tid >> 2, ng = tid & 3;
    const int m = m0 + mrow;
    unsigned short h[16];
    #pragma unroll
    for (int j = 0; j < 4; ++j) {
        const float4 t = ld4(Dct + (size_t)m*N_ + n0 + ng*16 + j*4);
        h[4*j+0]=f2bf(t.x); h[4*j+1]=f2bf(t.y); h[4*j+2]=f2bf(t.z); h[4*j+3]=f2bf(t.w);
    }
    unsigned int w[8];
    #pragma unroll
    for (int j = 0; j < 8; ++j) w[j] = (unsigned int)h[2*j] | ((unsigned int)h[2*j+1]<<16);
    const int fm = m >> 4;
    #pragma unroll
    for (int s = 0; s < 2; ++s) {
        const int u = 2*ng + s;                   // 0..7
        const int fk = (n0 >> 5) + (u >> 2);
        const int lane = (m & 15) + (u & 3) * 16;
        unsigned short* dst = DctA + ((size_t)(fm*64 + fk)*64 + lane)*8;
        *(uint4*)dst = *(uint4*)&w[s*4];
    }
    #pragma unroll
    for (int j = 0; j < 16; ++j) T[(ng*16+j)*72 + mrow] = h[j];
    __syncthreads();
    const int n = tid >> 2, mg = tid & 3;
    uint4 a  = *(uint4*)&T[n*72 + mg*16];
    uint4 b2 = *(uint4*)&T[n*72 + mg*16 + 8];
    unsigned short* dt = DctT + (size_t)(n0+n)*M_ + m0 + mg*16;
    *(uint4*)dt = a; *(uint4*)(dt+8) = b2;
}

// ---------------- K1: Qd/Kd/Vd = Dct @ (scaled/masked X), MFMA bf16 ----------
// BARRIER-FREE / LDS-FREE. 1152 single-wave blocks (64 thr): (panel, mh, dh).
// Wave owns 128m x 32d, K=2048, BK=32 (64 steps), everything in registers:
//   A-frag: 1 coalesced 1KB load/frag from frag-linear DctA (L2-hot), depth-2.
//   B-frag: 16 column loads of X directly in MFMA B layout
//           (lane: d = dh*32+nf*16+(lane&15), k = kg*8+j, kg=lane>>4), depth-2.
//   mask: two L1-hot ld4 per step; cvt fp32->bf16 + pack in VALU; no sync at all.
// XCD swizzle: the 4 sibling waves of a panel are adjacent -> same XCD L2.
__global__ __launch_bounds__(64, 2)
void gemm_qkv(const float* __restrict__ Q, const float* __restrict__ K,
              const float* __restrict__ V, const float* __restrict__ mask,
              const unsigned short* __restrict__ DctA,
              float* __restrict__ Qd, float* __restrict__ Kd, float* __restrict__ Vd)
{
    const int wg = blockIdx.x;
    const int id = (wg & 7) * 144 + (wg >> 3);   // 1152 = 8 XCD chunks x 144
    const int sub   = id & 3;                    // (mh, dh): siblings adjacent
    const int panel = id >> 2;                   // 0..287
    const int mh = sub >> 1, dh = sub & 1;
    const int bh = panel % BH_;
    const int tz = panel / BH_;
    const int b  = bh / H_;
    const float scale = 0.35355339059327373f;
    const float* X; float* Y; float smul; int um;
    if (tz==0)      { X=Q; Y=Qd; smul=scale; um=0; }
    else if (tz==1) { X=K; Y=Kd; smul=scale; um=1; }
    else            { X=V; Y=Vd; smul=1.0f;  um=1; }
    X += (size_t)bh*N_*D_;
    Y += (size_t)bh*M_*D_ + (size_t)mh*128*D_;

    const int lane = threadIdx.x & 63;
    const int l15  = lane & 15, kg = lane >> 4;
    // A: fm = mh*8 + fa ; frag addr = DctA + ((fm*64 + fk)*64 + lane)*8
    const unsigned short* abase = DctA + (size_t)(mh*8)*32768 + (size_t)lane*8;
    // X columns for nf=0,1 : d = dh*32 + nf*16 + l15 ; row k = kg*8 + j
    const float* xc0 = X + (size_t)(kg*8)*D_ + dh*32 + l15;
    const float* xc1 = xc0 + 16;
    const float* mbase = mask + (size_t)b*N_ + kg*8;

    f32x4 acc[8][2];
    #pragma unroll
    for (int i = 0; i < 8; ++i)
        #pragma unroll
        for (int j = 0; j < 2; ++j) { acc[i][j].x=0.f; acc[i][j].y=0.f; acc[i][j].z=0.f; acc[i][j].w=0.f; }

    short8v pa[8], pb[8];          // A-frag sets (fa = 0..7)
    float   xA0[8], xA1[8], xB0[8], xB1[8];
    float4  mA0, mA1, mB0, mB1;

    #define A_LOAD(P, FK) do {                                                \
        _Pragma("unroll")                                                     \
        for (int fa_ = 0; fa_ < 8; ++fa_)                                     \
            P[fa_] = *(const short8v*)(abase + (size_t)(fa_*64 + (FK))*512);  \
    } while(0)

    #define X_LOAD(X0, X1, M0, M1, FK) do {                                   \
        const float* p0_ = xc0 + (size_t)(FK)*32*D_;                          \
        const float* p1_ = xc1 + (size_t)(FK)*32*D_;                          \
        _Pragma("unroll")                                                     \
        for (int j_ = 0; j_ < 8; ++j_) {                                      \
            X0[j_] = p0_[(size_t)j_*D_];                                      \
            X1[j_] = p1_[(size_t)j_*D_];                                      \
        }                                                                     \
        M0 = ld4(mbase + (size_t)(FK)*32);                                    \
        M1 = ld4(mbase + (size_t)(FK)*32 + 4);                                \
    } while(0)

    #define COMPUTE(P, X0, X1, M0, M1) do {                                   \
        float f_[8];                                                          \
        f_[0]=um?smul*M0.x:smul; f_[1]=um?smul*M0.y:smul;                     \
        f_[2]=um?smul*M0.z:smul; f_[3]=um?smul*M0.w:smul;                     \
        f_[4]=um?smul*M1.x:smul; f_[5]=um?smul*M1.y:smul;                     \
        f_[6]=um?smul*M1.z:smul; f_[7]=um?smul*M1.w:smul;                     \
        unsigned int u0_[4], u1_[4];                                          \
        _Pragma("unroll")                                                     \
        for (int c_ = 0; c_ < 4; ++c_) {                                      \
            u0_[c_] = pack2(X0[2*c_]*f_[2*c_], X0[2*c_+1]*f_[2*c_+1]);        \
            u1_[c_] = pack2(X1[2*c_]*f_[2*c_], X1[2*c_+1]*f_[2*c_+1]);        \
        }                                                                     \
        short8v b0_ = *(short8v*)&u0_[0];                                     \
        short8v b1_ = *(short8v*)&u1_[0];                                     \
        _Pragma("unroll")                                                     \
        for (int fa_ = 0; fa_ < 8; ++fa_) {                                   \
            acc[fa_][0] = __builtin_amdgcn_mfma_f32_16x16x32_bf16(P[fa_], b0_, acc[fa_][0], 0, 0, 0); \
            acc[fa_][1] = __builtin_amdgcn_mfma_f32_16x16x32_bf16(P[fa_], b1_, acc[fa_][1], 0, 0, 0); \
        }                                                                     \
    } while(0)

    // ---- prologue: steps 0,1 in flight
    A_LOAD(pa, 0);  X_LOAD(xA0, xA1, mA0, mA1, 0);
    A_LOAD(pb, 1);  X_LOAD(xB0, xB1, mB0, mB1, 1);

    // ---- main loop: 64 steps, depth-2, no sync whatsoever
    for (int tb = 0; tb < 62; tb += 2) {
        COMPUTE(pa, xA0, xA1, mA0, mA1);
        A_LOAD(pa, tb+2);  X_LOAD(xA0, xA1, mA0, mA1, tb+2);
        COMPUTE(pb, xB0, xB1, mB0, mB1);
        A_LOAD(pb, tb+3);  X_LOAD(xB0, xB1, mB0, mB1, tb+3);
    }
    COMPUTE(pa, xA0, xA1, mA0, mA1);   // t=62
    COMPUTE(pb, xB0, xB1, mB0, mB1);   // t=63

    // ---- epilogue: col = lane&15 (d), row = (lane>>4)*4 + r (m)
    #pragma unroll
    for (int fa = 0; fa < 8; ++fa)
        #pragma unroll
        for (int nf = 0; nf < 2; ++nf)
            #pragma unroll
            for (int r = 0; r < 4; ++r) {
                const int m = fa*16 + kg*4 + r;
                const int d = dh*32 + nf*16 + l15;
                Y[(size_t)m*D_ + d] = acc[fa][nf][r];
            }
    #undef A_LOAD
    #undef X_LOAD
    #undef COMPUTE
}

// ---------------- K2: fused energy -> softmax -> ctx (fp32), bf16 transposed out
__global__ __launch_bounds__(256)
void attn_kernel(const float* __restrict__ Qd, const float* __restrict__ Kd,
                 const float* __restrict__ Vd, unsigned short* __restrict__ CtxT)
{
    __shared__ __align__(16) float S[M_][D_];    // 64 KB
    const int mt = blockIdx.x;
    const int bh = blockIdx.y;
    const float* qd = Qd + (size_t)bh * M_ * D_;
    const float* kd = Kd + (size_t)bh * M_ * D_;
    const float* vd = Vd + (size_t)bh * M_ * D_;

    const int tid = threadIdx.x;
    const int r = tid >> 2, sub = tid & 3;
    const int m = mt * 64 + r;

    float q[64];
    #pragma unroll
    for (int g = 0; g < 16; ++g) {
        const float4 t = ld4(qd + (size_t)m * D_ + g*4);
        q[4*g+0] = t.x; q[4*g+1] = t.y; q[4*g+2] = t.z; q[4*g+3] = t.w;
    }

    #pragma unroll
    for (int it = 0; it < 16; ++it) {
        const int i = tid + it*256;
        const int k = i >> 4, g = i & 15;
        const float4 t = ld4(kd + (size_t)i * 4);
        *(float4*)(&S[k][(g ^ (k & 3)) * 4]) = t;
    }
    __syncthreads();

    float e[64];
    #pragma unroll
    for (int kk = 0; kk < 64; ++kk) {
        const int k = kk*4 + sub;
        float acc = 0.f;
        #pragma unroll
        for (int g = 0; g < 16; ++g) {
            const float4 t = ld4(&S[k][(g ^ sub) * 4]);
            acc = fmaf(q[4*g+0], t.x, acc);
            acc = fmaf(q[4*g+1], t.y, acc);
            acc = fmaf(q[4*g+2], t.z, acc);
            acc = fmaf(q[4*g+3], t.w, acc);
        }
        e[kk] = acc;
    }

    float mx = e[0];
    #pragma unroll
    for (int kk = 1; kk < 64; ++kk) mx = fmaxf(mx, e[kk]);
    mx = fmaxf(mx, __shfl_xor(mx, 1));
    mx = fmaxf(mx, __shfl_xor(mx, 2));
    float sum = 0.f;
    #pragma unroll
    for (int kk = 0; kk < 64; ++kk) { e[kk] = __expf(e[kk] - mx); sum += e[kk]; }
    sum += __shfl_xor(sum, 1);
    sum += __shfl_xor(sum, 2);
    const float inv = 1.0f / sum;

    __syncthreads();
    #pragma unroll
    for (int it = 0; it < 16; ++it) {
        const int i = tid + it*256;
        const int k = i >> 4, g = i & 15;
        const float4 t = ld4(vd + (size_t)i * 4);
        *(float4*)(&S[k][(g ^ (k & 3)) * 4]) = t;
    }
    __syncthreads();

    float c[64] = {};
    #pragma unroll
    for (int kk = 0; kk < 64; ++kk) {
        const int k = kk*4 + sub;
        const float a = e[kk];
        #pragma unroll
        for (int g = 0; g < 16; ++g) {
            const float4 t = ld4(&S[k][(g ^ sub) * 4]);
            c[4*g+0] = fmaf(a, t.x, c[4*g+0]);
            c[4*g+1] = fmaf(a, t.y, c[4*g+1]);
            c[4*g+2] = fmaf(a, t.z, c[4*g+2]);
            c[4*g+3] = fmaf(a, t.w, c[4*g+3]);
        }
    }
    #pragma unroll
    for (int d = 0; d < 64; ++d) {
        c[d] += __shfl_xor(c[d], 1);
        c[d] += __shfl_xor(c[d], 2);
    }

    __syncthreads();
    unsigned short* T = (unsigned short*)&S[0][0];   // [64 d][72 m] ushorts
    #pragma unroll
    for (int g = 0; g < 16; ++g) {
        const int d = sub*16 + g;
        T[d*72 + r] = f2bf(c[d]*inv);
    }
    __syncthreads();
    const int d2 = tid >> 2, mg = tid & 3;
    uint4 w0 = *(uint4*)&T[d2*72 + mg*16];
    uint4 w1 = *(uint4*)&T[d2*72 + mg*16 + 8];
    unsigned short* dst = CtxT + (size_t)bh*D_*M_ + (size_t)d2*M_ + mt*64 + mg*16;
    *(uint4*)dst = w0; *(uint4*)(dst+8) = w1;
}

// ---------------- K3: x = DctT @ ctx_t^T, MFMA bf16 ------------------------
__global__ __launch_bounds__(128, 2)
void gemm_out(const unsigned short* __restrict__ DctT, const unsigned short* __restrict__ CtxT,
              float* __restrict__ Out)
{
    __shared__ __align__(16) unsigned short Asw[128*64];
    __shared__ __align__(16) unsigned short Bsw[64*64];
    const int nt = blockIdx.x, bh = blockIdx.y;
    const int n0 = nt*128;
    const unsigned short* ct = CtxT + (size_t)bh*D_*M_;
    float* out = Out + (size_t)bh*N_*D_;
    const int tid = threadIdx.x;
    const int lane = tid & 63, wave = tid >> 6;

    f32x4 acc[4][4];
    #pragma unroll
    for (int i = 0; i < 4; ++i)
        #pragma unroll
        for (int j = 0; j < 4; ++j) { acc[i][j].x=0.f; acc[i][j].y=0.f; acc[i][j].z=0.f; acc[i][j].w=0.f; }

    for (int step = 0; step < 4; ++step) {
        const int k0 = step*64;
        if (step) __syncthreads();
        const int ch = tid & 7;
        #pragma unroll
        for (int rr = 0; rr < 8; ++rr) {
            const int r = (tid>>3) + rr*16;
            const uint4 v = *(const uint4*)(DctT + (size_t)(n0+r)*M_ + k0 + ch*8);
            *(uint4*)((char*)Asw + r*128 + ((ch*16) ^ ((r&7)<<4))) = v;
        }
        #pragma unroll
        for (int rr = 0; rr < 4; ++rr) {
            const int d = (tid>>3) + rr*16;
            const uint4 v = *(const uint4*)(ct + (size_t)d*M_ + k0 + ch*8);
            *(uint4*)((char*)Bsw + d*128 + ((ch*16) ^ (((d>>1)&7)<<4))) = v;
        }
        __syncthreads();
        #pragma unroll
        for (int kh = 0; kh < 2; ++kh) {
            const int colb = kh*64 + (lane>>4)*16;
            short8v a[4], bb[4];
            #pragma unroll
            for (int mf = 0; mf < 4; ++mf) {
                const int r = wave*64 + mf*16 + (lane&15);
                a[mf] = *(const short8v*)((char*)Asw + r*128 + (colb ^ ((r&7)<<4)));
            }
            #pragma unroll
            for (int nf = 0; nf < 4; ++nf) {
                const int r = nf*16 + (lane&15);
                bb[nf] = *(const short8v*)((char*)Bsw + r*128 + (colb ^ (((r>>1)&7)<<4)));
            }
            #pragma unroll
            for (int mf = 0; mf < 4; ++mf)
                #pragma unroll
                for (int nf = 0; nf < 4; ++nf)
                    acc[mf][nf] = __builtin_amdgcn_mfma_f32_16x16x32_bf16(a[mf], bb[nf], acc[mf][nf], 0, 0, 0);
        }
    }
    #pragma unroll
    for (int mf = 0; mf < 4; ++mf)
        #pragma unroll
        for (int nf = 0; nf < 4; ++nf)
            #pragma unroll
            for (int r = 0; r < 4; ++r) {
                const int n = n0 + wave*64 + mf*16 + (lane>>4)*4 + r;
                const int d = nf*16 + (lane&15);
                out[(size_t)n*D_ + d] = acc[mf][nf][r];
            }
}

extern "C" void kernel_launch(void* const* d_in, const int* in_sizes, int n_in,
                              void* d_out, int out_size, void* d_ws, size_t ws_size,
                              hipStream_t stream) {
    const float* Q    = (const float*)d_in[0];
    const float* K    = (const float*)d_in[1];
    const float* V    = (const float*)d_in[2];
    const float* mask = (const float*)d_in[3];
    const float* Dct  = (const float*)d_in[4];
    float* out = (float*)d_out;

    const size_t per = (size_t)BH_ * M_ * D_;          // 1,572,864
    float* wsf = (float*)d_ws;
    float* Qd = wsf;
    float* Kd = Qd + per;
    float* Vd = Kd + per;
    unsigned short* CtxT = (unsigned short*)(Vd + per);  // per ushorts
    unsigned short* DctA = CtxT + per;                   // 524288 (frag-linear)
    unsigned short* DctT = DctA + (size_t)M_ * N_;       // 524288

    dct_prep_kernel<<<dim3(N_/64, M_/64), 256, 0, stream>>>(Dct, DctA, DctT);
    gemm_qkv<<<dim3(1152), 64, 0, stream>>>(Q, K, V, mask, DctA, Qd, Kd, Vd);
    attn_kernel<<<dim3(M_/64, BH_), 256, 0, stream>>>(Qd, Kd, Vd, CtxT);
    gemm_out<<<dim3(N_/128, BH_), 128, 0, stream>>>(DctT, CtxT, out);
}

// Round 12
// 84.561 us; speedup vs baseline: 1.4888x; 1.4888x over previous
//
#include <hip/hip_runtime.h>
#include <hip/hip_bf16.h>
#include <cstddef>

#define B_ 8
#define H_ 12
#define N_ 2048
#define D_ 64
#define M_ 256
#define BH_ (B_*H_)

typedef __attribute__((ext_vector_type(8))) short short8v;
typedef __attribute__((ext_vector_type(4))) float f32x4;

static __device__ __forceinline__ float4 ld4(const float* p){ return *(const float4*)p; }

static __device__ __forceinline__ unsigned short f2bf(float x){
    union { float f; unsigned int u; } v; v.f = x;
    unsigned int r = v.u + 0x7FFFu + ((v.u >> 16) & 1u);
    return (unsigned short)(r >> 16);
}
static __device__ __forceinline__ unsigned int pack2(float a, float b){
    return (unsigned int)f2bf(a) | ((unsigned int)f2bf(b) << 16);
}

// ---------------- K0: Dct fp32 -> DctA (MFMA frag-linear bf16) + DctT bf16 ----
__global__ __launch_bounds__(256)
void dct_prep_kernel(const float* __restrict__ Dct, unsigned short* __restrict__ DctA,
                     unsigned short* __restrict__ DctT)
{
    __shared__ __align__(16) unsigned short T[64*72];
    const int n0 = blockIdx.x * 64, m0 = blockIdx.y * 64;
    const int tid = threadIdx.x;
    const int mrow = tid >> 2, ng = tid & 3;
    const int m = m0 + mrow;
    unsigned short h[16];
    #pragma unroll
    for (int j = 0; j < 4; ++j) {
        const float4 t = ld4(Dct + (size_t)m*N_ + n0 + ng*16 + j*4);
        h[4*j+0]=f2bf(t.x); h[4*j+1]=f2bf(t.y); h[4*j+2]=f2bf(t.z); h[4*j+3]=f2bf(t.w);
    }
    unsigned int w[8];
    #pragma unroll
    for (int j = 0; j < 8; ++j) w[j] = (unsigned int)h[2*j] | ((unsigned int)h[2*j+1]<<16);
    const int fm = m >> 4;
    #pragma unroll
    for (int s = 0; s < 2; ++s) {
        const int u = 2*ng + s;                   // 0..7
        const int fk = (n0 >> 5) + (u >> 2);
        const int lane = (m & 15) + (u & 3) * 16;
        unsigned short* dst = DctA + ((size_t)(fm*64 + fk)*64 + lane)*8;
        *(uint4*)dst = *(uint4*)&w[s*4];
    }
    #pragma unroll
    for (int j = 0; j < 16; ++j) T[(ng*16+j)*72 + mrow] = h[j];
    __syncthreads();
    const int n = tid >> 2, mg = tid & 3;
    uint4 a  = *(uint4*)&T[n*72 + mg*16];
    uint4 b2 = *(uint4*)&T[n*72 + mg*16 + 8];
    unsigned short* dt = DctT + (size_t)(n0+n)*M_ + m0 + mg*16;
    *(uint4*)dt = a; *(uint4*)(dt+8) = b2;
}

// ---------------- K1: Qd/Kd/Vd = Dct @ (scaled/masked X), MFMA bf16 ----------
// R10 version (proven 77.6 us): 576 blocks = (panel,half), 256 thr (4 waves),
// 128m x 64d per block, BK=128 (16 steps), depth-2 A/X register prefetch,
// lgkmcnt-only barrier, XOR-swizzled B LDS, mask via one-time LDS table.
__global__ __launch_bounds__(256, 2)
void gemm_qkv(const float* __restrict__ Q, const float* __restrict__ K,
              const float* __restrict__ V, const float* __restrict__ mask,
              const unsigned short* __restrict__ DctA,
              float* __restrict__ Qd, float* __restrict__ Kd, float* __restrict__ Vd)
{
    __shared__ __align__(16) unsigned short Bsw[2][64*128];  // 2 x 16 KB, row 256 B
    __shared__ __align__(16) float Msk[N_];                  // 8 KB: smul * mask
    const int wg = blockIdx.x;
    const int id = (wg & 7) * 72 + (wg >> 3);   // 576 = 8 XCD chunks x 72
    const int half  = id & 1;
    const int panel = id >> 1;                  // 0..287
    const int bh = panel % BH_;
    const int tz = panel / BH_;
    const int b  = bh / H_;
    const float scale = 0.35355339059327373f;
    const float* X; float* Y; float smul; int um;
    if (tz==0)      { X=Q; Y=Qd; smul=scale; um=0; }
    else if (tz==1) { X=K; Y=Kd; smul=scale; um=1; }
    else            { X=V; Y=Vd; smul=1.0f;  um=1; }
    X += (size_t)bh*N_*D_;
    Y += (size_t)bh*M_*D_ + (size_t)half*128*D_;

    const int tid  = threadIdx.x;
    const int lane = tid & 63, wv = tid >> 6;
    const unsigned short* abase = DctA + (size_t)(half*8 + wv*2)*32768 + (size_t)lane*8;
    const float* xcol = X + lane;
    const int swz = (lane & 7) << 4;

    f32x4 acc[2][4];
    #pragma unroll
    for (int i = 0; i < 2; ++i)
        #pragma unroll
        for (int j = 0; j < 4; ++j) { acc[i][j].x=0.f; acc[i][j].y=0.f; acc[i][j].z=0.f; acc[i][j].w=0.f; }

    short8v pa[2][4], pb[2][4];
    float xrA[32], xrB[32];

    #define A_LOAD(P, T) do {                                                 \
        _Pragma("unroll")                                                     \
        for (int mf_ = 0; mf_ < 2; ++mf_)                                     \
            _Pragma("unroll")                                                 \
            for (int kh_ = 0; kh_ < 4; ++kh_)                                 \
                P[mf_][kh_] = *(const short8v*)(abase + (size_t)(mf_*64 + 4*(T)+kh_)*512); \
    } while(0)

    #define X_LOAD(XR, K0) do {                                               \
        const float* xp_ = xcol + (size_t)((K0) + wv*32) * D_;                \
        _Pragma("unroll")                                                     \
        for (int i_ = 0; i_ < 32; ++i_) XR[i_] = xp_[(size_t)i_*D_];          \
    } while(0)

    #define WRITE_B(XR, BUF, K0) do {                                         \
        const float4* mrow_ = (const float4*)&Msk[(K0) + wv*32];              \
        float fmv_[32];                                                       \
        _Pragma("unroll")                                                     \
        for (int j_ = 0; j_ < 8; ++j_) {                                      \
            const float4 t_ = mrow_[j_];                                      \
            fmv_[4*j_]=t_.x; fmv_[4*j_+1]=t_.y; fmv_[4*j_+2]=t_.z; fmv_[4*j_+3]=t_.w; \
        }                                                                     \
        _Pragma("unroll")                                                     \
        for (int c_ = 0; c_ < 4; ++c_) {                                      \
            uint4 w_;                                                         \
            w_.x = pack2(XR[8*c_+0]*fmv_[8*c_+0], XR[8*c_+1]*fmv_[8*c_+1]);   \
            w_.y = pack2(XR[8*c_+2]*fmv_[8*c_+2], XR[8*c_+3]*fmv_[8*c_+3]);   \
            w_.z = pack2(XR[8*c_+4]*fmv_[8*c_+4], XR[8*c_+5]*fmv_[8*c_+5]);   \
            w_.w = pack2(XR[8*c_+6]*fmv_[8*c_+6], XR[8*c_+7]*fmv_[8*c_+7]);   \
            *(uint4*)((char*)&Bsw[BUF][0] + lane*256 + ((wv*64 + c_*16) ^ swz)) = w_; \
        }                                                                     \
    } while(0)

    #define COMPUTE(BUF, P) do {                                              \
        _Pragma("unroll")                                                     \
        for (int kh_ = 0; kh_ < 4; ++kh_) {                                   \
            const int colb_ = kh_*64 + (lane>>4)*16;                          \
            short8v b_[4];                                                    \
            _Pragma("unroll")                                                 \
            for (int nf_ = 0; nf_ < 4; ++nf_) {                               \
                const int rr_ = nf_*16 + (lane&15);                           \
                b_[nf_] = *(const short8v*)((char*)&Bsw[BUF][0] + rr_*256 + (colb_ ^ ((rr_&7)<<4))); \
            }                                                                 \
            _Pragma("unroll")                                                 \
            for (int mf_ = 0; mf_ < 2; ++mf_)                                 \
                _Pragma("unroll")                                             \
                for (int nf_ = 0; nf_ < 4; ++nf_)                             \
                    acc[mf_][nf_] = __builtin_amdgcn_mfma_f32_16x16x32_bf16(P[mf_][kh_], b_[nf_], acc[mf_][nf_], 0, 0, 0); \
        }                                                                     \
    } while(0)

    #define BARJ() do { asm volatile("s_waitcnt lgkmcnt(0)" ::: "memory");    \
                        __builtin_amdgcn_sched_barrier(0);                    \
                        __builtin_amdgcn_s_barrier(); } while(0)

    {
        #pragma unroll
        for (int c = 0; c < 2; ++c) {
            const int idx = (tid + c*256) * 4;
            float4 v;
            if (um) {
                v = ld4(mask + (size_t)b*N_ + idx);
                v.x *= smul; v.y *= smul; v.z *= smul; v.w *= smul;
            } else { v.x = smul; v.y = smul; v.z = smul; v.w = smul; }
            *(float4*)&Msk[idx] = v;
        }
    }
    A_LOAD(pa, 0);
    X_LOAD(xrA, 0);
    X_LOAD(xrB, 128);
    __syncthreads();
    WRITE_B(xrA, 0, 0);
    BARJ();

    #define STEP_EVEN(T) do {                                                 \
        A_LOAD(pb, (T)+1);                                                    \
        X_LOAD(xrA, ((T)+2)*128);                                             \
        COMPUTE(0, pa);                                                       \
        __builtin_amdgcn_sched_barrier(0);                                    \
        WRITE_B(xrB, 1, ((T)+1)*128);                                         \
        BARJ();                                                               \
    } while(0)
    #define STEP_ODD(T) do {                                                  \
        A_LOAD(pa, (T)+1);                                                    \
        X_LOAD(xrB, ((T)+2)*128);                                             \
        COMPUTE(1, pb);                                                       \
        __builtin_amdgcn_sched_barrier(0);                                    \
        WRITE_B(xrA, 0, ((T)+1)*128);                                         \
        BARJ();                                                               \
    } while(0)

    for (int tb = 0; tb < 14; tb += 2) {
        STEP_EVEN(tb);
        STEP_ODD(tb+1);
    }
    A_LOAD(pb, 15);
    COMPUTE(0, pa);
    __builtin_amdgcn_sched_barrier(0);
    WRITE_B(xrB, 1, 15*128);
    BARJ();
    COMPUTE(1, pb);

    #pragma unroll
    for (int mf = 0; mf < 2; ++mf)
        #pragma unroll
        for (int nf = 0; nf < 4; ++nf)
            #pragma unroll
            for (int r = 0; r < 4; ++r) {
                const int m = wv*32 + mf*16 + (lane>>4)*4 + r;
                const int d = nf*16 + (lane&15);
                Y[(size_t)m*D_ + d] = acc[mf][nf][r];
            }
    #undef A_LOAD
    #undef X_LOAD
    #undef WRITE_B
    #undef COMPUTE
    #undef BARJ
    #undef STEP_EVEN
    #undef STEP_ODD
}

// ---------------- K2: MFMA attention: energy=QdKd^T -> softmax(reg) -> PV ----
// Per block: (mt 0..3, bh). 256 thr / 4 waves; wave w owns m rows [16w,16w+16).
// Phase A: stage QA[64][64] + KB[256][64] bf16 (rows along d, XOR swz) -> energy
// via mfma(QA-frag, KB-frag), acc[16] covers 256 k2. Softmax fully in-register
// on the D-layout (16 nf regs + shfl_xor within 16-lane group). Phase B: P ->
// PL[64][256] bf16 (scalar stores, row-XOR swz); Vd -> VT[64][256] transposed
// bf16 (coalesced reads, pack2 writes). PV via mfma(PL-frag, VT-frag); rows of
// PV-D match energy-D so inv[r] applies at write. Output via T[64][72] bounce.
__global__ __launch_bounds__(256, 2)
void attn_kernel(const float* __restrict__ Qd, const float* __restrict__ Kd,
                 const float* __restrict__ Vd, unsigned short* __restrict__ CtxT)
{
    __shared__ __align__(16) char LB[65536];
    unsigned short* QA = (unsigned short*)(LB);          // [64][64]  rows 128 B (phase A)
    unsigned short* KB = (unsigned short*)(LB + 8192);   // [256][64] rows 128 B (phase A)
    unsigned short* PL = (unsigned short*)(LB);          // [64][256] rows 512 B (phase B)
    unsigned short* VT = (unsigned short*)(LB + 32768);  // [64][256] rows 512 B (phase B)
    unsigned short* T  = (unsigned short*)(LB);          // [64][72]  (phase C)

    const int mt = blockIdx.x, bh = blockIdx.y;
    const float* qd = Qd + (size_t)bh*M_*D_ + (size_t)mt*64*D_;
    const float* kd = Kd + (size_t)bh*M_*D_;
    const float* vd = Vd + (size_t)bh*M_*D_;
    const int tid  = threadIdx.x;
    const int lane = tid & 63, wv = tid >> 6;
    const int l15  = lane & 15, kg = lane >> 4;
    const int swz  = (l15 & 7) << 4;

    // ---- phase A: stage QA + KB (bf16, rows along d, XOR-swizzled rows)
    {
        const int row = tid >> 2, q = tid & 3;
        {
            const float* p = qd + (size_t)row*D_ + q*16;
            const float4 a = ld4(p), b2 = ld4(p+4), c = ld4(p+8), d = ld4(p+12);
            uint4 w0, w1;
            w0.x=pack2(a.x,a.y);  w0.y=pack2(a.z,a.w);  w0.z=pack2(b2.x,b2.y); w0.w=pack2(b2.z,b2.w);
            w1.x=pack2(c.x,c.y);  w1.y=pack2(c.z,c.w);  w1.z=pack2(d.x,d.y);  w1.w=pack2(d.z,d.w);
            const int s = (row & 7) << 4;
            *(uint4*)((char*)QA + row*128 + ((q*32)      ^ s)) = w0;
            *(uint4*)((char*)QA + row*128 + ((q*32 + 16) ^ s)) = w1;
        }
        #pragma unroll
        for (int c0 = 0; c0 < 4; ++c0) {
            const int krow = c0*64 + row;
            const float* p = kd + (size_t)krow*D_ + q*16;
            const float4 a = ld4(p), b2 = ld4(p+4), c = ld4(p+8), d = ld4(p+12);
            uint4 w0, w1;
            w0.x=pack2(a.x,a.y);  w0.y=pack2(a.z,a.w);  w0.z=pack2(b2.x,b2.y); w0.w=pack2(b2.z,b2.w);
            w1.x=pack2(c.x,c.y);  w1.y=pack2(c.z,c.w);  w1.z=pack2(d.x,d.y);  w1.w=pack2(d.z,d.w);
            const int s = (krow & 7) << 4;
            *(uint4*)((char*)KB + krow*128 + ((q*32)      ^ s)) = w0;
            *(uint4*)((char*)KB + krow*128 + ((q*32 + 16) ^ s)) = w1;
        }
    }
    __syncthreads();

    // ---- energy: acc[nf] = Qd(m-frag) x Kd(k2-frag nf), contraction over d
    f32x4 acc[16];
    #pragma unroll
    for (int i = 0; i < 16; ++i) { acc[i].x=0.f; acc[i].y=0.f; acc[i].z=0.f; acc[i].w=0.f; }
    #pragma unroll
    for (int kh = 0; kh < 2; ++kh) {
        const int colb = kh*64 + kg*16;
        const short8v af = *(const short8v*)((char*)QA + (wv*16 + l15)*128 + (colb ^ swz));
        #pragma unroll
        for (int nf = 0; nf < 16; ++nf) {
            const short8v bf = *(const short8v*)((char*)KB + (nf*16 + l15)*128 + (colb ^ swz));
            acc[nf] = __builtin_amdgcn_mfma_f32_16x16x32_bf16(af, bf, acc[nf], 0, 0, 0);
        }
    }

    // ---- softmax in-register on D-layout: lane holds rows m=16wv+4kg+r, cols nf*16+l15
    float inv[4];
    #pragma unroll
    for (int r = 0; r < 4; ++r) {
        float mx = acc[0][r];
        #pragma unroll
        for (int nf = 1; nf < 16; ++nf) mx = fmaxf(mx, acc[nf][r]);
        mx = fmaxf(mx, __shfl_xor(mx, 1));
        mx = fmaxf(mx, __shfl_xor(mx, 2));
        mx = fmaxf(mx, __shfl_xor(mx, 4));
        mx = fmaxf(mx, __shfl_xor(mx, 8));
        float sm = 0.f;
        #pragma unroll
        for (int nf = 0; nf < 16; ++nf) {
            const float p = __expf(acc[nf][r] - mx);
            acc[nf][r] = p; sm += p;
        }
        sm += __shfl_xor(sm, 1);
        sm += __shfl_xor(sm, 2);
        sm += __shfl_xor(sm, 4);
        sm += __shfl_xor(sm, 8);
        inv[r] = 1.0f / sm;
    }
    __syncthreads();   // all waves done reading QA/KB

    // ---- phase B staging: P -> PL (scalar bf16, row-XOR swz); Vd -> VT transposed
    {
        const int rowbase = wv*16 + kg*4;
        #pragma unroll
        for (int nf = 0; nf < 16; ++nf)
            #pragma unroll
            for (int r = 0; r < 4; ++r) {
                const int rowP = rowbase + r;
                const int byte = rowP*512 + ((((nf*16 + l15)*2)) ^ ((rowP & 7) << 4));
                *(unsigned short*)((char*)PL + byte) = f2bf(acc[nf][r]);
            }
    }
    {
        const int dcol = tid & 63, kq = tid >> 6;
        const int vs = (dcol & 7) << 4;
        #pragma unroll
        for (int cp = 0; cp < 32; ++cp) {
            const int k2 = kq*64 + cp*2;
            const float v0 = vd[(size_t)k2*D_ + dcol];
            const float v1 = vd[(size_t)(k2+1)*D_ + dcol];
            const int byte = dcol*512 + ((k2*2) ^ vs);
            *(unsigned int*)((char*)VT + byte) = pack2(v0, v1);
        }
    }
    __syncthreads();

    // ---- PV: ctx = P x Vd, contraction over k2 (8 kf steps of 32)
    f32x4 c2[4];
    #pragma unroll
    for (int i = 0; i < 4; ++i) { c2[i].x=0.f; c2[i].y=0.f; c2[i].z=0.f; c2[i].w=0.f; }
    #pragma unroll
    for (int kf = 0; kf < 8; ++kf) {
        const int colb = kf*64 + kg*16;
        const short8v a = *(const short8v*)((char*)PL + (wv*16 + l15)*512 + (colb ^ swz));
        #pragma unroll
        for (int nf2 = 0; nf2 < 4; ++nf2) {
            const int drow = nf2*16 + l15;
            const short8v bb = *(const short8v*)((char*)VT + drow*512 + (colb ^ swz));
            c2[nf2] = __builtin_amdgcn_mfma_f32_16x16x32_bf16(a, bb, c2[nf2], 0, 0, 0);
        }
    }
    __syncthreads();   // done reading PL/VT

    // ---- output bounce T[64 d][72 m], then coalesced CtxT[d][m] write
    {
        const int rowbase = wv*16 + kg*4;
        #pragma unroll
        for (int nf2 = 0; nf2 < 4; ++nf2)
            #pragma unroll
            for (int r = 0; r < 4; ++r) {
                const int d = nf2*16 + l15;
                T[d*72 + rowbase + r] = f2bf(c2[nf2][r] * inv[r]);
            }
    }
    __syncthreads();
    {
        const int d2 = tid >> 2, mg = tid & 3;
        uint4 w0 = *(uint4*)&T[d2*72 + mg*16];
        uint4 w1 = *(uint4*)&T[d2*72 + mg*16 + 8];
        unsigned short* dst = CtxT + (size_t)bh*D_*M_ + (size_t)d2*M_ + mt*64 + mg*16;
        *(uint4*)dst = w0; *(uint4*)(dst+8) = w1;
    }
}

// ---------------- K3: x = DctT @ ctx_t^T, MFMA bf16 ------------------------
__global__ __launch_bounds__(128, 2)
void gemm_out(const unsigned short* __restrict__ DctT, const unsigned short* __restrict__ CtxT,
              float* __restrict__ Out)
{
    __shared__ __align__(16) unsigned short Asw[128*64];
    __shared__ __align__(16) unsigned short Bsw[64*64];
    const int nt = blockIdx.x, bh = blockIdx.y;
    const int n0 = nt*128;
    const unsigned short* ct = CtxT + (size_t)bh*D_*M_;
    float* out = Out + (size_t)bh*N_*D_;
    const int tid = threadIdx.x;
    const int lane = tid & 63, wave = tid >> 6;

    f32x4 acc[4][4];
    #pragma unroll
    for (int i = 0; i < 4; ++i)
        #pragma unroll
        for (int j = 0; j < 4; ++j) { acc[i][j].x=0.f; acc[i][j].y=0.f; acc[i][j].z=0.f; acc[i][j].w=0.f; }

    for (int step = 0; step < 4; ++step) {
        const int k0 = step*64;
        if (step) __syncthreads();
        const int ch = tid & 7;
        #pragma unroll
        for (int rr = 0; rr < 8; ++rr) {
            const int r = (tid>>3) + rr*16;
            const uint4 v = *(const uint4*)(DctT + (size_t)(n0+r)*M_ + k0 + ch*8);
            *(uint4*)((char*)Asw + r*128 + ((ch*16) ^ ((r&7)<<4))) = v;
        }
        #pragma unroll
        for (int rr = 0; rr < 4; ++rr) {
            const int d = (tid>>3) + rr*16;
            const uint4 v = *(const uint4*)(ct + (size_t)d*M_ + k0 + ch*8);
            *(uint4*)((char*)Bsw + d*128 + ((ch*16) ^ (((d>>1)&7)<<4))) = v;
        }
        __syncthreads();
        #pragma unroll
        for (int kh = 0; kh < 2; ++kh) {
            const int colb = kh*64 + (lane>>4)*16;
            short8v a[4], bb[4];
            #pragma unroll
            for (int mf = 0; mf < 4; ++mf) {
                const int r = wave*64 + mf*16 + (lane&15);
                a[mf] = *(const short8v*)((char*)Asw + r*128 + (colb ^ ((r&7)<<4)));
            }
            #pragma unroll
            for (int nf = 0; nf < 4; ++nf) {
                const int r = nf*16 + (lane&15);
                bb[nf] = *(const short8v*)((char*)Bsw + r*128 + (colb ^ (((r>>1)&7)<<4)));
            }
            #pragma unroll
            for (int mf = 0; mf < 4; ++mf)
                #pragma unroll
                for (int nf = 0; nf < 4; ++nf)
                    acc[mf][nf] = __builtin_amdgcn_mfma_f32_16x16x32_bf16(a[mf], bb[nf], acc[mf][nf], 0, 0, 0);
        }
    }
    #pragma unroll
    for (int mf = 0; mf < 4; ++mf)
        #pragma unroll
        for (int nf = 0; nf < 4; ++nf)
            #pragma unroll
            for (int r = 0; r < 4; ++r) {
                const int n = n0 + wave*64 + mf*16 + (lane>>4)*4 + r;
                const int d = nf*16 + (lane&15);
                out[(size_t)n*D_ + d] = acc[mf][nf][r];
            }
}

extern "C" void kernel_launch(void* const* d_in, const int* in_sizes, int n_in,
                              void* d_out, int out_size, void* d_ws, size_t ws_size,
                              hipStream_t stream) {
    const float* Q    = (const float*)d_in[0];
    const float* K    = (const float*)d_in[1];
    const float* V    = (const float*)d_in[2];
    const float* mask = (const float*)d_in[3];
    const float* Dct  = (const float*)d_in[4];
    float* out = (float*)d_out;

    const size_t per = (size_t)BH_ * M_ * D_;          // 1,572,864
    float* wsf = (float*)d_ws;
    float* Qd = wsf;
    float* Kd = Qd + per;
    float* Vd = Kd + per;
    unsigned short* CtxT = (unsigned short*)(Vd + per);  // per ushorts
    unsigned short* DctA = CtxT + per;                   // 524288 (frag-linear)
    unsigned short* DctT = DctA + (size_t)M_ * N_;       // 524288

    dct_prep_kernel<<<dim3(N_/64, M_/64), 256, 0, stream>>>(Dct, DctA, DctT);
    gemm_qkv<<<dim3(576), 256, 0, stream>>>(Q, K, V, mask, DctA, Qd, Kd, Vd);
    attn_kernel<<<dim3(M_/64, BH_), 256, 0, stream>>>(Qd, Kd, Vd, CtxT);
    gemm_out<<<dim3(N_/128, BH_), 128, 0, stream>>>(DctT, CtxT, out);
}